// Round 1
// baseline (452.893 us; speedup 1.0000x reference)
//
#include <hip/hip_runtime.h>
#include <math.h>

#define TT 2048   // tokens
#define HH 1024   // hidden
#define EE 8      // experts
#define II 2048   // intermediate
#define N1 4096   // 2*II
#define ALPHA 1.702f
#define LIMIT 7.0f

typedef __attribute__((ext_vector_type(8))) short short8;
typedef __attribute__((ext_vector_type(4))) float floatx4;

__device__ __forceinline__ short f2bf(float f) {
  union { float f; unsigned u; } v; v.f = f;
  unsigned r = (v.u + 0x7fffu + ((v.u >> 16) & 1u)) >> 16;
  return (short)r;
}
__device__ __forceinline__ float bf2f(unsigned short s) {
  union { unsigned u; float f; } v; v.u = ((unsigned)s) << 16;
  return v.f;
}

// ---------------- router: logits -> softmax -> top2 ----------------
__global__ __launch_bounds__(256) void router_kernel(
    const float* __restrict__ x, const float* __restrict__ rw,
    const float* __restrict__ rb, int* __restrict__ topk_idx,
    float* __restrict__ topk_w) {
  const int t = blockIdx.x;
  const float* xr = x + (size_t)t * HH;
  const int lane = threadIdx.x & 63;
  const int wave = threadIdx.x >> 6;
  float xv[16];
#pragma unroll
  for (int i = 0; i < 16; i++) xv[i] = xr[lane + i * 64];
  __shared__ float logits[EE];
#pragma unroll
  for (int ee = 0; ee < 2; ee++) {
    const int e = wave * 2 + ee;
    const float* wr = rw + (size_t)e * HH;
    float s = 0.f;
#pragma unroll
    for (int i = 0; i < 16; i++) s += xv[i] * wr[lane + i * 64];
#pragma unroll
    for (int off = 32; off > 0; off >>= 1) s += __shfl_down(s, off, 64);
    if (lane == 0) logits[e] = s + rb[e];
  }
  __syncthreads();
  if (threadIdx.x == 0) {
    float l[EE], sc[EE];
    float mx = -3.4e38f;
    for (int i = 0; i < EE; i++) { l[i] = logits[i]; mx = fmaxf(mx, l[i]); }
    float sum = 0.f;
    for (int i = 0; i < EE; i++) { sc[i] = expf(l[i] - mx); sum += sc[i]; }
    const float inv = 1.f / sum;
    int i0 = 0;
    for (int i = 1; i < EE; i++) if (sc[i] > sc[i0]) i0 = i;
    int i1 = (i0 == 0) ? 1 : 0;
    for (int i = 0; i < EE; i++) if (i != i0 && sc[i] > sc[i1]) i1 = i;
    topk_idx[t * 2 + 0] = i0;
    topk_idx[t * 2 + 1] = i1;
    topk_w[t * 2 + 0] = sc[i0] * inv;
    topk_w[t * 2 + 1] = sc[i1] * inv;
  }
}

// ---------------- token->expert compaction ----------------
__global__ void assign_kernel(const int* __restrict__ topk_idx,
                              int* __restrict__ counts, int* __restrict__ rows) {
  const int id = blockIdx.x * blockDim.x + threadIdx.x;
  if (id >= TT * 2) return;
  const int e = topk_idx[id];
  const int slot = atomicAdd(&counts[e], 1);
  rows[e * TT + slot] = id;  // entry = t*2 + k
}

// ---------------- GEMM1: gathered x (f32->bf16) x gate_up_proj[e] -> gu (bf16) --
__global__ __launch_bounds__(256) void gemm_gu(
    const float* __restrict__ x, const float* __restrict__ gup,
    const float* __restrict__ gub, const int* __restrict__ counts,
    const int* __restrict__ rows, unsigned short* __restrict__ gu) {
  const int e = blockIdx.z, mtile = blockIdx.y, ntile = blockIdx.x;
  const int count = counts[e];
  if (mtile * 128 >= count) return;
  const int* rl = rows + e * TT + mtile * 128;
  __shared__ short As[128][40];  // [m][k], +8 pad -> 2-way (free) b128 banks
  __shared__ short Bs[128][40];  // [n][k]
  const int tid = threadIdx.x;
  const int lane = tid & 63, wave = tid >> 6;
  const int wm = (wave & 1) << 6, wn = (wave >> 1) << 6;
  const int quad = lane >> 4, r16 = lane & 15;

  const int arow = tid >> 2, akoct = tid & 3;
  const int cr0 = (mtile * 128 + arow < count) ? arow : (count - 1 - mtile * 128);
  const int cr1 = (mtile * 128 + arow + 64 < count) ? arow + 64 : (count - 1 - mtile * 128);
  const float* a0 = x + (size_t)(rl[cr0] >> 1) * HH;
  const float* a1 = x + (size_t)(rl[cr1] >> 1) * HH;

  const int bn = tid & 127, bk = tid >> 7;
  const float* bb = gup + (size_t)e * HH * N1 + ntile * 128 + bn;

  floatx4 acc[4][4] = {};

  for (int k0 = 0; k0 < HH; k0 += 32) {
    __syncthreads();
    {  // stage A (two 64-row halves), convert f32->bf16, ds_write_b128
      const float4* p = (const float4*)(a0 + k0 + akoct * 8);
      float4 v0 = p[0], v1 = p[1];
      short8 s;
      s[0]=f2bf(v0.x); s[1]=f2bf(v0.y); s[2]=f2bf(v0.z); s[3]=f2bf(v0.w);
      s[4]=f2bf(v1.x); s[5]=f2bf(v1.y); s[6]=f2bf(v1.z); s[7]=f2bf(v1.w);
      *(short8*)&As[arow][akoct * 8] = s;
      p = (const float4*)(a1 + k0 + akoct * 8);
      v0 = p[0]; v1 = p[1];
      s[0]=f2bf(v0.x); s[1]=f2bf(v0.y); s[2]=f2bf(v0.z); s[3]=f2bf(v0.w);
      s[4]=f2bf(v1.x); s[5]=f2bf(v1.y); s[6]=f2bf(v1.z); s[7]=f2bf(v1.w);
      *(short8*)&As[arow + 64][akoct * 8] = s;
    }
    {  // stage B transposed: coalesced f32 row reads, pack 8 k's, b128 write
      const float* p = bb + (size_t)(k0 + bk * 8) * N1;
      short8 s;
#pragma unroll
      for (int j = 0; j < 8; j++) s[j] = f2bf(p[(size_t)j * N1]);
      *(short8*)&Bs[bn][bk * 8] = s;
      p = bb + (size_t)(k0 + (bk + 2) * 8) * N1;
#pragma unroll
      for (int j = 0; j < 8; j++) s[j] = f2bf(p[(size_t)j * N1]);
      *(short8*)&Bs[bn][(bk + 2) * 8] = s;
    }
    __syncthreads();
    short8 af[4], bf_[4];
#pragma unroll
    for (int i = 0; i < 4; i++)
      af[i] = *(const short8*)&As[wm + i * 16 + r16][quad * 8];
#pragma unroll
    for (int j = 0; j < 4; j++)
      bf_[j] = *(const short8*)&Bs[wn + j * 16 + r16][quad * 8];
#pragma unroll
    for (int i = 0; i < 4; i++)
#pragma unroll
      for (int j = 0; j < 4; j++)
        acc[i][j] = __builtin_amdgcn_mfma_f32_16x16x32_bf16(af[i], bf_[j], acc[i][j], 0, 0, 0);
  }
#pragma unroll
  for (int i = 0; i < 4; i++) {
#pragma unroll
    for (int reg = 0; reg < 4; reg++) {
      const int rrow = wm + i * 16 + quad * 4 + reg;
      if (mtile * 128 + rrow < count) {
        const int ent = rl[rrow];
        unsigned short* orow = gu + (size_t)ent * N1 + ntile * 128;
#pragma unroll
        for (int j = 0; j < 4; j++) {
          const int c = wn + j * 16 + r16;
          const float v = acc[i][j][reg] + gub[e * N1 + ntile * 128 + c];
          orow[c] = (unsigned short)f2bf(v);
        }
      }
    }
  }
}

// ---------------- activation: gu -> act ----------------
__global__ void act_kernel(const unsigned short* __restrict__ gu,
                           unsigned short* __restrict__ act) {
  const int id = blockIdx.x * blockDim.x + threadIdx.x;
  if (id >= TT * 2 * II) return;
  const int r = id >> 11;          // / II
  const int i = id & (II - 1);     // % II
  float g = bf2f(gu[(size_t)r * N1 + i]);
  float u = bf2f(gu[(size_t)r * N1 + II + i]);
  g = fminf(g, LIMIT);
  u = fminf(fmaxf(u, -LIMIT), LIMIT);
  const float glu = g / (1.f + expf(-g * ALPHA));
  act[(size_t)r * II + i] = (unsigned short)f2bf((u + 1.f) * glu);
}

// ---------------- GEMM2: act (bf16) x down_proj[e] -> dout (f32) --------------
__global__ __launch_bounds__(256) void gemm_down(
    const unsigned short* __restrict__ act, const float* __restrict__ dp,
    const float* __restrict__ db, const int* __restrict__ counts,
    const int* __restrict__ rows, float* __restrict__ dout) {
  const int e = blockIdx.z, mtile = blockIdx.y, ntile = blockIdx.x;
  const int count = counts[e];
  if (mtile * 128 >= count) return;
  const int* rl = rows + e * TT + mtile * 128;
  __shared__ short As[128][40];
  __shared__ short Bs[128][40];
  const int tid = threadIdx.x;
  const int lane = tid & 63, wave = tid >> 6;
  const int wm = (wave & 1) << 6, wn = (wave >> 1) << 6;
  const int quad = lane >> 4, r16 = lane & 15;

  const int arow = tid >> 2, akoct = tid & 3;
  const int cr0 = (mtile * 128 + arow < count) ? arow : (count - 1 - mtile * 128);
  const int cr1 = (mtile * 128 + arow + 64 < count) ? arow + 64 : (count - 1 - mtile * 128);
  const unsigned short* a0 = act + (size_t)rl[cr0] * II;
  const unsigned short* a1 = act + (size_t)rl[cr1] * II;

  const int bn = tid & 127, bk = tid >> 7;
  const float* bb = dp + (size_t)e * II * HH + ntile * 128 + bn;

  floatx4 acc[4][4] = {};

  for (int k0 = 0; k0 < II; k0 += 32) {
    __syncthreads();
    {  // stage A: already bf16, straight 16B copies
      *(short8*)&As[arow][akoct * 8] = *(const short8*)(a0 + k0 + akoct * 8);
      *(short8*)&As[arow + 64][akoct * 8] = *(const short8*)(a1 + k0 + akoct * 8);
    }
    {
      const float* p = bb + (size_t)(k0 + bk * 8) * HH;
      short8 s;
#pragma unroll
      for (int j = 0; j < 8; j++) s[j] = f2bf(p[(size_t)j * HH]);
      *(short8*)&Bs[bn][bk * 8] = s;
      p = bb + (size_t)(k0 + (bk + 2) * 8) * HH;
#pragma unroll
      for (int j = 0; j < 8; j++) s[j] = f2bf(p[(size_t)j * HH]);
      *(short8*)&Bs[bn][(bk + 2) * 8] = s;
    }
    __syncthreads();
    short8 af[4], bf_[4];
#pragma unroll
    for (int i = 0; i < 4; i++)
      af[i] = *(const short8*)&As[wm + i * 16 + r16][quad * 8];
#pragma unroll
    for (int j = 0; j < 4; j++)
      bf_[j] = *(const short8*)&Bs[wn + j * 16 + r16][quad * 8];
#pragma unroll
    for (int i = 0; i < 4; i++)
#pragma unroll
      for (int j = 0; j < 4; j++)
        acc[i][j] = __builtin_amdgcn_mfma_f32_16x16x32_bf16(af[i], bf_[j], acc[i][j], 0, 0, 0);
  }
#pragma unroll
  for (int i = 0; i < 4; i++) {
#pragma unroll
    for (int reg = 0; reg < 4; reg++) {
      const int rrow = wm + i * 16 + quad * 4 + reg;
      if (mtile * 128 + rrow < count) {
        const int ent = rl[rrow];
        float* orow = dout + (size_t)ent * HH + ntile * 128;
#pragma unroll
        for (int j = 0; j < 4; j++) {
          const int c = wn + j * 16 + r16;
          orow[c] = acc[i][j][reg] + db[e * HH + ntile * 128 + c];
        }
      }
    }
  }
}

// ---------------- combine: out = w0*d(t,0) + w1*d(t,1) ----------------
__global__ void combine_kernel(const float* __restrict__ dout,
                               const float* __restrict__ tw,
                               float* __restrict__ out) {
  const int id = blockIdx.x * blockDim.x + threadIdx.x;
  const int t = id >> 8;            // H/4 = 256 float4 per token
  const int h = (id & 255) * 4;
  const float w0 = tw[t * 2], w1 = tw[t * 2 + 1];
  const float4 a = *(const float4*)(dout + (size_t)(2 * t) * HH + h);
  const float4 b = *(const float4*)(dout + (size_t)(2 * t + 1) * HH + h);
  float4 o;
  o.x = w0 * a.x + w1 * b.x;
  o.y = w0 * a.y + w1 * b.y;
  o.z = w0 * a.z + w1 * b.z;
  o.w = w0 * a.w + w1 * b.w;
  *(float4*)(out + (size_t)t * HH + h) = o;
}

extern "C" void kernel_launch(void* const* d_in, const int* in_sizes, int n_in,
                              void* d_out, int out_size, void* d_ws, size_t ws_size,
                              hipStream_t stream) {
  const float* x   = (const float*)d_in[0];
  const float* rw  = (const float*)d_in[1];
  const float* rb  = (const float*)d_in[2];
  const float* gup = (const float*)d_in[3];
  const float* gub = (const float*)d_in[4];
  const float* dp  = (const float*)d_in[5];
  const float* db  = (const float*)d_in[6];
  float* out = (float*)d_out;

  char* ws = (char*)d_ws;
  int*   topk_idx = (int*)(ws + 0);                       // 16 KB
  float* topk_w   = (float*)(ws + 16384);                 // 16 KB
  int*   counts   = (int*)(ws + 32768);                   // 256 B
  int*   rows     = (int*)(ws + 33024);                   // 64 KB
  unsigned short* gu  = (unsigned short*)(ws + 131072);               // 33.5 MB
  unsigned short* act = (unsigned short*)(ws + 131072 + 33554432);    // 16.8 MB
  float* dout = (float*)(ws + 131072 + 33554432 + 16777216);          // 16.8 MB

  router_kernel<<<TT, 256, 0, stream>>>(x, rw, rb, topk_idx, topk_w);
  hipMemsetAsync(counts, 0, 64, stream);
  assign_kernel<<<(TT * 2 + 255) / 256, 256, 0, stream>>>(topk_idx, counts, rows);
  gemm_gu<<<dim3(N1 / 128, TT / 128, EE), 256, 0, stream>>>(x, gup, gub, counts, rows, gu);
  act_kernel<<<(TT * 2 * II) / 256, 256, 0, stream>>>(gu, act);
  gemm_down<<<dim3(HH / 128, TT / 128, EE), 256, 0, stream>>>(act, dp, db, counts, rows, dout);
  combine_kernel<<<(TT * HH / 4) / 256, 256, 0, stream>>>(dout, topk_w, out);
}